// Round 3
// baseline (423.065 us; speedup 1.0000x reference)
//
#include <hip/hip_runtime.h>
#include <cstdint>
#include <cstddef>
#include <cstdio>

#define B_   4
#define L_   4096
#define D_   1024
#define H_   16
#define BS_  64
#define HD_  64
#define NB_  64
#define SCALE_   0.125f
#define INV_TEMP (1.0f/0.7f)

typedef unsigned short bf16_t;

#ifndef __has_builtin
#define __has_builtin(x) 0
#endif
#if __has_builtin(__builtin_amdgcn_global_load_lds)
#define HAS_GLD 1
#else
#define HAS_GLD 0
#endif

#if HAS_GLD
#define GLD16(gp, lp) __builtin_amdgcn_global_load_lds(                        \
    (__attribute__((address_space(1))) void*)(uintptr_t)(gp),                  \
    (__attribute__((address_space(3))) void*)(unsigned int)(uintptr_t)(lp),    \
    16, 0, 0)
#endif

__device__ __forceinline__ float b2f(bf16_t u) {
    union { unsigned int i; float f; } c; c.i = ((unsigned int)u) << 16; return c.f;
}
__device__ __forceinline__ bf16_t f2b(float f) {
    union { float f; unsigned int i; } c; c.f = f;
    unsigned int r = c.i + 0x7FFFu + ((c.i >> 16) & 1u);   // RNE
    return (bf16_t)(r >> 16);
}

__device__ __forceinline__ void storeC(float* p, float v)  { *p = v; }
__device__ __forceinline__ void storeC(bf16_t* p, float v) { *p = f2b(v); }

using bf16x8 = __attribute__((ext_vector_type(8))) short;
using f32x4  = __attribute__((ext_vector_type(4))) float;

// ---------------------------------------------------------------------------
// fp32 -> bf16 elementwise (4 elems/thread)
// ---------------------------------------------------------------------------
__global__ __launch_bounds__(256) void f32_to_bf16_kernel(
    const float* __restrict__ src, bf16_t* __restrict__ dst, int n4)
{
    const int i = blockIdx.x * 256 + threadIdx.x;
    if (i < n4) {
        float4 v = *(const float4*)(src + (size_t)i * 4);
        ushort4 o = {f2b(v.x), f2b(v.y), f2b(v.z), f2b(v.w)};
        *(ushort4*)(dst + (size_t)i * 4) = o;
    }
}

// ---------------------------------------------------------------------------
// fp32 [R][C] -> bf16 [C][R] transpose (32x32 LDS tile, block 32x8)
// ---------------------------------------------------------------------------
__global__ __launch_bounds__(256) void transpose_f32_bf16_kernel(
    const float* __restrict__ src, bf16_t* __restrict__ dst, int R, int C)
{
    __shared__ float t[32][33];
    const int c0 = blockIdx.x * 32, r0 = blockIdx.y * 32;
    for (int i = threadIdx.y; i < 32; i += 8)
        t[i][threadIdx.x] = src[(size_t)(r0 + i) * C + c0 + threadIdx.x];
    __syncthreads();
    for (int i = threadIdx.y; i < 32; i += 8)
        dst[(size_t)(c0 + i) * R + r0 + threadIdx.x] = f2b(t[threadIdx.x][i]);
}

// ---------------------------------------------------------------------------
// 256x256 8-phase MFMA bf16 GEMM (T1+T2+T3+T4+T5): C = A @ Bt^T + bias.
// 8 waves (2M x 4N), BK=64, double-buffered 128 KiB LDS, XOR-swizzled LDS,
// counted vmcnt(4) once per K-tile, XCD-aware blockIdx swizzle.
// ---------------------------------------------------------------------------
#if HAS_GLD
#define SGA(tt, hb, dst)                                                       \
    GLD16(gAb + (size_t)((hb) * 128) * K + (size_t)(tt) * 64,                  \
          (dst) + (((hb) * 128 + w * 16) * 64));                               \
    GLD16(gAb + (size_t)((hb) * 128 + 8) * K + (size_t)(tt) * 64,              \
          (dst) + (((hb) * 128 + w * 16 + 8) * 64))
#define SGB(tt, hb, dst)                                                       \
    GLD16(gBb + (size_t)((hb) * 128) * K + (size_t)(tt) * 64,                  \
          (dst) + (((hb) * 128 + w * 16) * 64));                               \
    GLD16(gBb + (size_t)((hb) * 128 + 8) * K + (size_t)(tt) * 64,              \
          (dst) + (((hb) * 128 + w * 16 + 8) * 64))
#else
#define SGA(tt, hb, dst)                                                       \
    *(bf16x8*)((dst) + (((hb) * 128 + w * 16) * 64) + lane * 8) =              \
        *(const bf16x8*)(gAb + (size_t)((hb) * 128) * K + (size_t)(tt) * 64);  \
    *(bf16x8*)((dst) + (((hb) * 128 + w * 16 + 8) * 64) + lane * 8) =          \
        *(const bf16x8*)(gAb + (size_t)((hb) * 128 + 8) * K + (size_t)(tt) * 64)
#define SGB(tt, hb, dst)                                                       \
    *(bf16x8*)((dst) + (((hb) * 128 + w * 16) * 64) + lane * 8) =              \
        *(const bf16x8*)(gBb + (size_t)((hb) * 128) * K + (size_t)(tt) * 64);  \
    *(bf16x8*)((dst) + (((hb) * 128 + w * 16 + 8) * 64) + lane * 8) =          \
        *(const bf16x8*)(gBb + (size_t)((hb) * 128 + 8) * K + (size_t)(tt) * 64)
#endif

#define PHASE(ABUF, p, STAGE, ENDWAIT)                                         \
  {                                                                            \
    bf16x8 a0k0 = *(const bf16x8*)&(ABUF)[aRow0 + (2*(p))   * 1024 + csw[0]];  \
    bf16x8 a0k1 = *(const bf16x8*)&(ABUF)[aRow0 + (2*(p))   * 1024 + csw[1]];  \
    bf16x8 a1k0 = *(const bf16x8*)&(ABUF)[aRow0 + (2*(p)+1) * 1024 + csw[0]];  \
    bf16x8 a1k1 = *(const bf16x8*)&(ABUF)[aRow0 + (2*(p)+1) * 1024 + csw[1]];  \
    STAGE;                                                                     \
    __builtin_amdgcn_s_barrier();                                              \
    asm volatile("s_waitcnt lgkmcnt(0)" ::: "memory");                         \
    __builtin_amdgcn_s_setprio(1);                                             \
    _Pragma("unroll")                                                          \
    for (int fn = 0; fn < 4; ++fn) {                                           \
      acc[2*(p)][fn]   = __builtin_amdgcn_mfma_f32_16x16x32_bf16(              \
          a0k0, bq[fn][0], acc[2*(p)][fn], 0, 0, 0);                           \
      acc[2*(p)][fn]   = __builtin_amdgcn_mfma_f32_16x16x32_bf16(              \
          a0k1, bq[fn][1], acc[2*(p)][fn], 0, 0, 0);                           \
      acc[2*(p)+1][fn] = __builtin_amdgcn_mfma_f32_16x16x32_bf16(              \
          a1k0, bq[fn][0], acc[2*(p)+1][fn], 0, 0, 0);                         \
      acc[2*(p)+1][fn] = __builtin_amdgcn_mfma_f32_16x16x32_bf16(              \
          a1k1, bq[fn][1], acc[2*(p)+1][fn], 0, 0, 0);                         \
    }                                                                          \
    __builtin_amdgcn_s_setprio(0);                                             \
    ENDWAIT;                                                                   \
    __builtin_amdgcn_s_barrier();                                              \
    asm volatile("" ::: "memory");                                             \
  }

#define KTILE(ABUF, BBUF, NABUF, t)                                            \
  {                                                                            \
    bf16x8 bq[4][2];                                                           \
    _Pragma("unroll")                                                          \
    for (int fn = 0; fn < 4; ++fn) {                                           \
      bq[fn][0] = *(const bf16x8*)&(BBUF)[bRow0 + fn * 1024 + csw[0]];         \
      bq[fn][1] = *(const bf16x8*)&(BBUF)[bRow0 + fn * 1024 + csw[1]];         \
    }                                                                          \
    const bool stA = ((t) + 1 < KT), stB = ((t) + 2 < KT);                     \
    PHASE(ABUF, 0, if (stA) { SGA((t) + 1, 0, NABUF); }, )                     \
    PHASE(ABUF, 1, if (stA) { SGA((t) + 1, 1, NABUF); }, )                     \
    PHASE(ABUF, 2, if (stB) { SGB((t) + 2, 0, BBUF); }, )                      \
    PHASE(ABUF, 3, if (stB) { SGB((t) + 2, 1, BBUF); },                        \
          if ((t) + 1 < KT) {                                                  \
            if (stB) { asm volatile("s_waitcnt vmcnt(4)" ::: "memory"); }      \
            else     { asm volatile("s_waitcnt vmcnt(0)" ::: "memory"); }      \
          })                                                                   \
  }

template<typename TC>
__global__ __launch_bounds__(512, 2) void gemm256_8phase_kernel(
    const bf16_t* __restrict__ A, const bf16_t* __restrict__ Bt,
    const float* __restrict__ bias, TC* __restrict__ C,
    int M, int N, int K)
{
    // [buf][A|B][256 rows][64 cols] bf16 = 128 KiB
    __shared__ __align__(16) short sm[65536];
    short* const smA0 = sm;
    short* const smB0 = sm + 16384;
    short* const smA1 = sm + 32768;
    short* const smB1 = sm + 49152;

    const int tid  = threadIdx.x;
    const int lane = tid & 63;
    const int w    = tid >> 6;            // 8 waves: 2 (M) x 4 (N)
    const int wr   = w >> 2, wc = w & 3;
    const int ml   = lane & 15, q2 = lane >> 4;

    // T1: XCD-aware blockIdx swizzle (bijective when nwg % 8 == 0)
    const int gx  = gridDim.x;
    const int nwg = gx * gridDim.y;
    const int bid = blockIdx.y * gx + blockIdx.x;
    int swz = bid;
    if ((nwg & 7) == 0) swz = (bid & 7) * (nwg >> 3) + (bid >> 3);
    const int m0 = (swz / gx) * 256, n0 = (swz % gx) * 256;

    const int KT   = K >> 6;              // K-tiles of 64 (even; K=1024 -> 16)

    // ds_read addressing (swizzled: 16B-chunk ^= row&7; row&7 == ml&7)
    int csw[2];
    csw[0] = ((q2)     ^ (ml & 7)) * 8;
    csw[1] = ((4 + q2) ^ (ml & 7)) * 8;
    const int aRow0 = (wr * 128 + ml) * 64;
    const int bRow0 = (wc * 64  + ml) * 64;

    // staging source (pre-swizzled global address; gload_lds dest is linear)
    const int rl   = lane >> 3;                       // row-in-8
    const int scol = ((lane & 7) ^ rl) * 8;           // swizzled k-chunk
    const bf16_t* gAb = A  + (size_t)(m0 + w * 16 + rl) * K + scol;
    const bf16_t* gBb = Bt + (size_t)(n0 + w * 16 + rl) * K + scol;

    f32x4 acc[8][4];
    #pragma unroll
    for (int i = 0; i < 8; ++i)
        #pragma unroll
        for (int j = 0; j < 4; ++j)
            acc[i][j] = {0.f, 0.f, 0.f, 0.f};

    // prologue: A(0), B(0) -> buf0; B(1) -> buf1; wait all but B(1)'s 4 loads
    SGA(0, 0, smA0); SGA(0, 1, smA0);
    SGB(0, 0, smB0); SGB(0, 1, smB0);
    SGB(1, 0, smB1); SGB(1, 1, smB1);
    asm volatile("s_waitcnt vmcnt(4)" ::: "memory");
    __builtin_amdgcn_s_barrier();
    asm volatile("" ::: "memory");

    for (int t = 0; t < KT; t += 2) {
        KTILE(smA0, smB0, smA1, t);
        KTILE(smA1, smB1, smA0, t + 1);
    }

    // epilogue
    float bv[4];
    #pragma unroll
    for (int fn = 0; fn < 4; ++fn)
        bv[fn] = bias[n0 + wc * 64 + fn * 16 + ml];
    #pragma unroll
    for (int fm = 0; fm < 8; ++fm)
        #pragma unroll
        for (int fn = 0; fn < 4; ++fn)
            #pragma unroll
            for (int r = 0; r < 4; ++r) {
                const int row = m0 + wr * 128 + fm * 16 + q2 * 4 + r;
                const int col = n0 + wc * 64  + fn * 16 + ml;
                storeC(&C[(size_t)row * N + col], acc[fm][fn][r] + bv[fn]);
            }
}

#undef KTILE
#undef PHASE
#undef SGA
#undef SGB

// ---------------------------------------------------------------------------
// Block means: 4 waves/block, stride-4 token partition + LDS reduce.
// ---------------------------------------------------------------------------
__global__ __launch_bounds__(256) void block_repr_kernel(
    const bf16_t* __restrict__ qkv,
    float* __restrict__ q_repr, float* __restrict__ k_repr)
{
    __shared__ float red[2][4][64];
    const int blk = blockIdx.x;
    const int n  = blk & 63;
    const int bh = blk >> 6;
    const int h  = bh & 15, b = bh >> 4;
    const int d  = threadIdx.x & 63;
    const int ss = threadIdx.x >> 6;     // wave id 0..3
    const bf16_t* base = qkv + (size_t)(b * L_ + n * BS_) * (3 * D_) + h * HD_ + d;
    float sq = 0.f, sk = 0.f;
    for (int s = ss; s < BS_; s += 4) {
        sq += b2f(base[(size_t)s * (3 * D_)]);
        sk += b2f(base[(size_t)s * (3 * D_) + D_]);
    }
    red[0][ss][d] = sq;
    red[1][ss][d] = sk;
    __syncthreads();
    if (threadIdx.x < 64) {
        const int dd = threadIdx.x;
        q_repr[(size_t)blk * HD_ + dd] =
            (red[0][0][dd] + red[0][1][dd] + red[0][2][dd] + red[0][3][dd])
            * (1.0f / BS_);
    } else if (threadIdx.x < 128) {
        const int dd = threadIdx.x - 64;
        k_repr[(size_t)blk * HD_ + dd] =
            (red[1][0][dd] + red[1][1][dd] + red[1][2][dd] + red[1][3][dd])
            * (1.0f / BS_);
    }
}

// ---------------------------------------------------------------------------
// Gumbel-Sinkhorn: one block of 256 threads per (b,h). Thread (r, sub=tid&3)
// owns 16 elements (m = 4*mi+sub) of row r (row pass / sim) or col r (col
// pass). 4-lane __shfl_xor completes the 64-wide logsumexp.
// ---------------------------------------------------------------------------
__global__ __launch_bounds__(256) void sinkhorn_kernel(
    const float* __restrict__ q_repr, const float* __restrict__ k_repr,
    const float* __restrict__ gumbel, bf16_t* __restrict__ P_bf)
{
    __shared__ __align__(16) float qr[64 * 68];
    __shared__ __align__(16) float kr[64 * 68];
    __shared__ float la[64 * 65];
    const int bh  = blockIdx.x;
    const int tid = threadIdx.x;
    const int r   = tid >> 2;            // 0..63
    const int sub = tid & 3;

    for (int idx = tid; idx < 4096; idx += 256) {
        const int rr = idx >> 6, cc = idx & 63;
        qr[rr * 68 + cc] = q_repr[(size_t)bh * 4096 + idx];
        kr[rr * 68 + cc] = k_repr[(size_t)bh * 4096 + idx];
    }
    __syncthreads();

    // sim init: thread computes cols m = 4*mi+sub of row r
    {
        float acc[16];
        #pragma unroll
        for (int mi = 0; mi < 16; ++mi) acc[mi] = 0.f;
        for (int d4 = 0; d4 < 16; ++d4) {
            const float4 q = *(const float4*)&qr[r * 68 + d4 * 4];
            #pragma unroll
            for (int mi = 0; mi < 16; ++mi) {
                const float4 kv = *(const float4*)&kr[(4 * mi + sub) * 68 + d4 * 4];
                acc[mi] += q.x * kv.x + q.y * kv.y + q.z * kv.z + q.w * kv.w;
            }
        }
        #pragma unroll
        for (int mi = 0; mi < 16; ++mi) {
            const int m = 4 * mi + sub;
            la[r * 65 + m] = (acc[mi] * SCALE_
                + gumbel[(size_t)bh * 4096 + r * 64 + m]) * INV_TEMP;
        }
    }
    __syncthreads();

    for (int it = 0; it < 7; ++it) {
        {   // row pass: normalize row r over m
            float v[16];
            #pragma unroll
            for (int mi = 0; mi < 16; ++mi) v[mi] = la[r * 65 + 4 * mi + sub];
            float mx = v[0];
            #pragma unroll
            for (int mi = 1; mi < 16; ++mi) mx = fmaxf(mx, v[mi]);
            mx = fmaxf(mx, __shfl_xor(mx, 1, 64));
            mx = fmaxf(mx, __shfl_xor(mx, 2, 64));
            float sum = 0.f;
            #pragma unroll
            for (int mi = 0; mi < 16; ++mi) sum += expf(v[mi] - mx);
            sum += __shfl_xor(sum, 1, 64);
            sum += __shfl_xor(sum, 2, 64);
            const float lse = mx + logf(sum);
            #pragma unroll
            for (int mi = 0; mi < 16; ++mi) la[r * 65 + 4 * mi + sub] = v[mi] - lse;
        }
        __syncthreads();
        {   // col pass: normalize col r over rows
            float v[16];
            #pragma unroll
            for (int mi = 0; mi < 16; ++mi) v[mi] = la[(4 * mi + sub) * 65 + r];
            float mx = v[0];
            #pragma unroll
            for (int mi = 1; mi < 16; ++mi) mx = fmaxf(mx, v[mi]);
            mx = fmaxf(mx, __shfl_xor(mx, 1, 64));
            mx = fmaxf(mx, __shfl_xor(mx, 2, 64));
            float sum = 0.f;
            #pragma unroll
            for (int mi = 0; mi < 16; ++mi) sum += expf(v[mi] - mx);
            sum += __shfl_xor(sum, 1, 64);
            sum += __shfl_xor(sum, 2, 64);
            const float lse = mx + logf(sum);
            #pragma unroll
            for (int mi = 0; mi < 16; ++mi)
                la[(4 * mi + sub) * 65 + r] = v[mi] - lse;
        }
        __syncthreads();
    }

    #pragma unroll
    for (int mi = 0; mi < 16; ++mi) {
        const int m = 4 * mi + sub;
        P_bf[(size_t)bh * 4096 + r * 64 + m] = f2b(expf(la[r * 65 + m]));
    }
}

// ---------------------------------------------------------------------------
// MFMA soft-sort: per (b,h): out[n,f] = sum_m P[n,m] * src[m,f], f = s*64+d.
// Wave w owns token s = c*4+w. Staging: wave vector-loads its 64 K (or V)
// rows (128 B contiguous each, 8 rows per b128 wave-load) into a
// wave-PRIVATE LDS slice [64][68] (pad 68 -> ~2-way banks on write+read);
// bt fragments then gather from LDS (ds_read_u16, ~5.8 cyc) instead of
// 128 scalar 2 B global loads at 786 KB stride. No extra barriers (slices
// are wave-private; compiler orders ds_write->ds_read within wave).
// ---------------------------------------------------------------------------
__global__ __launch_bounds__(256) void sort_kv_mfma_kernel(
    const bf16_t* __restrict__ P_bf, const bf16_t* __restrict__ qkv,
    bf16_t* __restrict__ k_sorted, bf16_t* __restrict__ v_sorted)
{
    constexpr int TS = 72;
    constexpr int RS = 68;               // K/V row stride (shorts)
    __shared__ short Pl[64 * TS];
    __shared__ __align__(16) short Kst[4 * 64 * RS];
    const int tid = threadIdx.x, lane = tid & 63, w = tid >> 6;
    const int bh = blockIdx.y;
    const int h = bh & 15, b = bh >> 4;
    const int c = blockIdx.x;
    const int ml = lane & 15, q8 = (lane >> 4) * 8;

    // stage P[n][m] -> Pl bf16
    {
        const int r = tid >> 3, cc = (tid & 7) * 8;
        const bf16_t* ps = P_bf + (size_t)bh * (NB_ * NB_);
        *(bf16x8*)&Pl[r * TS + cc]        = *(const bf16x8*)&ps[r * 64 + cc];
        *(bf16x8*)&Pl[(r + 32) * TS + cc] = *(const bf16x8*)&ps[(r + 32) * 64 + cc];
    }
    __syncthreads();

    const int s = c * 4 + w;                       // token index within block
    const int fbase = c * 256 + w * 64;
    short* Kw = &Kst[w * 64 * RS];                 // wave-private slice
    const int srow = lane >> 3;                    // row-in-8 for staging
    const int sc8  = (lane & 7) * 8;               // 16 B segment

    for (int kv = 0; kv < 2; ++kv) {
        const bf16_t* src = qkv + ((size_t)(b * L_ + s)) * (3 * D_)
                          + (kv ? 2 * D_ : 1 * D_) + h * HD_;

        // stage 64 rows x 128 B into LDS (8 rows per wave-load)
        #pragma unroll
        for (int g = 0; g < 8; ++g) {
            const int m = g * 8 + srow;
            *(bf16x8*)&Kw[m * RS + sc8] =
                *(const bf16x8*)(src + (size_t)m * (BS_ * 3 * D_) + sc8);
        }

        // B-frags from LDS: bt[t][kt][j] = row(kt*32+q8+j), d = t*16+ml
        bf16x8 bt[4][2];
        #pragma unroll
        for (int kt = 0; kt < 2; ++kt)
            #pragma unroll
            for (int j = 0; j < 8; ++j) {
                const short* rp = &Kw[(kt * 32 + q8 + j) * RS + ml];
                #pragma unroll
                for (int t = 0; t < 4; ++t)
                    bt[t][kt][j] = rp[t * 16];
            }

        f32x4 acc[4][4];
        #pragma unroll
        for (int nt = 0; nt < 4; ++nt)
            #pragma unroll
            for (int t = 0; t < 4; ++t)
                acc[nt][t] = {0.f, 0.f, 0.f, 0.f};

        #pragma unroll
        for (int nt = 0; nt < 4; ++nt) {
            bf16x8 a0 = *(const bf16x8*)&Pl[(nt * 16 + ml) * TS + q8];
            bf16x8 a1 = *(const bf16x8*)&Pl[(nt * 16 + ml) * TS + 32 + q8];
            #pragma unroll
            for (int t = 0; t < 4; ++t) {
                acc[nt][t] = __builtin_amdgcn_mfma_f32_16x16x32_bf16(
                    a0, bt[t][0], acc[nt][t], 0, 0, 0);
                acc[nt][t] = __builtin_amdgcn_mfma_f32_16x16x32_bf16(
                    a1, bt[t][1], acc[nt][t], 0, 0, 0);
            }
        }

        // store: n = nt*16 + quad*4 + reg, f = fbase + t*16 + ml
        bf16_t* dst = (kv ? v_sorted : k_sorted) + (size_t)bh * (NB_ * BS_ * HD_);
        const int quad4 = (lane >> 4) * 4;
        #pragma unroll
        for (int nt = 0; nt < 4; ++nt)
            #pragma unroll
            for (int t = 0; t < 4; ++t)
                #pragma unroll
                for (int r = 0; r < 4; ++r)
                    dst[(size_t)(nt * 16 + quad4 + r) * (BS_ * HD_)
                        + fbase + t * 16 + ml] = f2b(acc[nt][t][r]);
    }
}

// ---------------------------------------------------------------------------
// MFMA block attention (verified round 6)
// ---------------------------------------------------------------------------
__global__ __launch_bounds__(256) void attn_mfma_kernel(
    const bf16_t* __restrict__ qkv, const bf16_t* __restrict__ k_sorted,
    const bf16_t* __restrict__ v_sorted, bf16_t* __restrict__ attn_out)
{
    constexpr int KS = 72, VS = 136, PS = 136;
    __shared__ short Ks[128 * KS];
    __shared__ short Vt[64 * VS];
    __shared__ short Psh[64 * PS];
    const int tid = threadIdx.x, lane = tid & 63, w = tid >> 6;
    const int n  = blockIdx.x & 63;
    const int bh = blockIdx.x >> 6;
    const int h = bh & 15, b = bh >> 4;
    const bool last = (n == NB_ - 1);

    const bf16_t* qb = qkv + (size_t)(b * L_ + n * BS_) * (3 * D_) + h * HD_;
    const bf16_t* kb = qb + D_;
    const bf16_t* vb = qb + 2 * D_;
    const size_t nextoff = ((size_t)bh * NB_ + (n + 1)) * (size_t)(BS_ * HD_);
    const bf16_t* kn = k_sorted + nextoff;
    const bf16_t* vn = v_sorted + nextoff;

    {
        const int col8 = (tid & 7) * 8, r0 = tid >> 3;
        const int jjmax = last ? 2 : 4;
        for (int jj = 0; jj < jjmax; ++jj) {
            const int row = jj * 32 + r0;
            const bf16_t* src = (row < 64)
                ? kb + (size_t)row * (3 * D_) + col8
                : kn + (size_t)(row - 64) * HD_ + col8;
            *(bf16x8*)&Ks[row * KS + col8] = *(const bf16x8*)src;
        }
    }
    {
        const int halves = last ? 1 : 2;
        for (int half = 0; half < halves; ++half) {
            for (int jj = 0; jj < 4; ++jj) {
                const int d0 = jj * 16 + w * 4;
                const bf16_t* src = (half == 0)
                    ? vb + (size_t)lane * (3 * D_) + d0
                    : vn + (size_t)lane * HD_ + d0;
                ushort4 u = *(const ushort4*)src;
                const int kcol = half * 64 + lane;
                Vt[(d0 + 0) * VS + kcol] = u.x;
                Vt[(d0 + 1) * VS + kcol] = u.y;
                Vt[(d0 + 2) * VS + kcol] = u.z;
                Vt[(d0 + 3) * VS + kcol] = u.w;
            }
        }
    }

    const int ml = lane & 15, quad = lane >> 4, q8 = quad * 8;
    const int m0 = w * 16;

    bf16x8 af0 = *(const bf16x8*)(qb + (size_t)(m0 + ml) * (3 * D_) + q8);
    bf16x8 af1 = *(const bf16x8*)(qb + (size_t)(m0 + ml) * (3 * D_) + 32 + q8);

    __syncthreads();

    const int ntile = last ? 4 : 8;
    f32x4 st[8];
    #pragma unroll
    for (int t = 0; t < 8; ++t) st[t] = {0.f, 0.f, 0.f, 0.f};
    for (int t = 0; t < ntile; ++t) {
        bf16x8 b0 = *(const bf16x8*)&Ks[(t * 16 + ml) * KS + q8];
        bf16x8 b1 = *(const bf16x8*)&Ks[(t * 16 + ml) * KS + 32 + q8];
        st[t] = __builtin_amdgcn_mfma_f32_16x16x32_bf16(af0, b0, st[t], 0, 0, 0);
        st[t] = __builtin_amdgcn_mfma_f32_16x16x32_bf16(af1, b1, st[t], 0, 0, 0);
    }

    #pragma unroll
    for (int reg = 0; reg < 4; ++reg) {
        float mx = -1e30f;
        for (int t = 0; t < ntile; ++t) mx = fmaxf(mx, st[t][reg] * SCALE_);
        #pragma unroll
        for (int xm = 1; xm <= 8; xm <<= 1)
            mx = fmaxf(mx, __shfl_xor(mx, xm, 64));
        float e[8];
        float sum = 0.f;
        for (int t = 0; t < ntile; ++t) {
            e[t] = __expf(st[t][reg] * SCALE_ - mx);
            sum += e[t];
        }
        #pragma unroll
        for (int xm = 1; xm <= 8; xm <<= 1)
            sum += __shfl_xor(sum, xm, 64);
        const float inv = 1.0f / sum;
        const int qrow = m0 + quad * 4 + reg;
        for (int t = 0; t < ntile; ++t)
            Psh[qrow * PS + t * 16 + ml] = f2b(e[t] * inv);
    }

    __syncthreads();

    const int ktv = last ? 2 : 4;
    f32x4 oacc[4];
    #pragma unroll
    for (int t = 0; t < 4; ++t) oacc[t] = {0.f, 0.f, 0.f, 0.f};
    for (int kt = 0; kt < ktv; ++kt) {
        bf16x8 pa = *(const bf16x8*)&Psh[(m0 + ml) * PS + kt * 32 + q8];
        #pragma unroll
        for (int t = 0; t < 4; ++t) {
            bf16x8 vf = *(const bf16x8*)&Vt[(t * 16 + ml) * VS + kt * 32 + q8];
            oacc[t] = __builtin_amdgcn_mfma_f32_16x16x32_bf16(pa, vf, oacc[t], 0, 0, 0);
        }
    }

    bf16_t* ob = attn_out + (size_t)(b * L_ + n * BS_) * D_ + h * HD_;
    #pragma unroll
    for (int t = 0; t < 4; ++t)
        #pragma unroll
        for (int reg = 0; reg < 4; ++reg) {
            const int qrow = m0 + quad * 4 + reg;
            ob[(size_t)qrow * D_ + t * 16 + ml] = f2b(oacc[t][reg]);
        }
}

// ---------------------------------------------------------------------------
extern "C" void kernel_launch(void* const* d_in, const int* in_sizes, int n_in,
                              void* d_out, int out_size, void* d_ws, size_t ws_size,
                              hipStream_t stream)
{
    const float* x      = (const float*)d_in[0];
    const float* gumbel = (const float*)d_in[1];
    const float* W_qkv  = (const float*)d_in[2];
    const float* b_qkv  = (const float*)d_in[3];
    const float* W_out  = (const float*)d_in[4];
    const float* b_out  = (const float*)d_in[5];
    float* out = (float*)d_out;

    const size_t need = 204472320ull;
    if (ws_size < need) {
        fprintf(stderr, "[kernel_launch] ws_size=%zu < need=%zu — aborting launch\n",
                ws_size, need);
        return;
    }

    bf16_t* qkv      = (bf16_t*)d_ws;
    bf16_t* attn_o   = qkv    + (size_t)B_ * L_ * 3 * D_;
    bf16_t* k_sorted = attn_o + (size_t)B_ * L_ * D_;
    bf16_t* v_sorted = k_sorted + (size_t)B_ * L_ * D_;
    float* q_repr    = (float*)(v_sorted + (size_t)B_ * L_ * D_);
    float* k_repr    = q_repr + (size_t)B_ * H_ * NB_ * HD_;
    bf16_t* P_bf     = (bf16_t*)(k_repr + (size_t)B_ * H_ * NB_ * HD_);

    bf16_t* x_bf   = (bf16_t*)d_out;               // d_out scratch until GEMM2
    bf16_t* Wqkv_t = x_bf + (size_t)B_ * L_ * D_;
    bf16_t* Wout_t = (bf16_t*)q_repr;              // dead after sinkhorn

    // 0a. x -> bf16
    f32_to_bf16_kernel<<<(B_ * L_ * D_ / 4 + 255) / 256, 256, 0, stream>>>(
        x, x_bf, B_ * L_ * D_ / 4);
    // 0b. W_qkv [1024,3072] -> Wqkv_t bf16 [3072,1024]
    transpose_f32_bf16_kernel<<<dim3(3 * D_ / 32, D_ / 32), dim3(32, 8), 0, stream>>>(
        W_qkv, Wqkv_t, D_, 3 * D_);

    // 1. QKV projection (256x256 8-phase MFMA bf16)
    gemm256_8phase_kernel<bf16_t>
        <<<dim3(3 * D_ / 256, B_ * L_ / 256), 512, 0, stream>>>(
        x_bf, Wqkv_t, b_qkv, qkv, B_ * L_, 3 * D_, D_);

    // 2. block means (4 waves/block)
    block_repr_kernel<<<B_ * H_ * NB_, 256, 0, stream>>>(qkv, q_repr, k_repr);

    // 3. Gumbel-Sinkhorn -> P (bf16), 256 threads/block
    sinkhorn_kernel<<<B_ * H_, 256, 0, stream>>>(q_repr, k_repr, gumbel, P_bf);

    // 4. soft-sort K/V blocks (MFMA, LDS-staged gather)
    sort_kv_mfma_kernel<<<dim3(16, B_ * H_), 256, 0, stream>>>(
        P_bf, qkv, k_sorted, v_sorted);

    // 5. block-local attention (MFMA)
    attn_mfma_kernel<<<B_ * H_ * NB_, 256, 0, stream>>>(
        qkv, k_sorted, v_sorted, attn_o);

    // 5b. W_out -> Wout_t bf16 [1024,1024]
    transpose_f32_bf16_kernel<<<dim3(D_ / 32, D_ / 32), dim3(32, 8), 0, stream>>>(
        W_out, Wout_t, D_, D_);

    // 6. output projection (256x256 8-phase MFMA bf16) -> fp32
    gemm256_8phase_kernel<float>
        <<<dim3(D_ / 256, B_ * L_ / 256), 512, 0, stream>>>(
        attn_o, Wout_t, b_out, out, B_ * L_, D_, D_);
}

// Round 4
// 414.127 us; speedup vs baseline: 1.0216x; 1.0216x over previous
//
#include <hip/hip_runtime.h>
#include <cstdint>
#include <cstddef>
#include <cstdio>

#define B_   4
#define L_   4096
#define D_   1024
#define H_   16
#define BS_  64
#define HD_  64
#define NB_  64
#define SCALE_   0.125f
#define INV_TEMP (1.0f/0.7f)

typedef unsigned short bf16_t;

#ifndef __has_builtin
#define __has_builtin(x) 0
#endif
#if __has_builtin(__builtin_amdgcn_global_load_lds)
#define HAS_GLD 1
#else
#define HAS_GLD 0
#endif

#if HAS_GLD
#define GLD16(gp, lp) __builtin_amdgcn_global_load_lds(                        \
    (__attribute__((address_space(1))) void*)(uintptr_t)(gp),                  \
    (__attribute__((address_space(3))) void*)(unsigned int)(uintptr_t)(lp),    \
    16, 0, 0)
#endif

__device__ __forceinline__ float b2f(bf16_t u) {
    union { unsigned int i; float f; } c; c.i = ((unsigned int)u) << 16; return c.f;
}
__device__ __forceinline__ bf16_t f2b(float f) {
    union { float f; unsigned int i; } c; c.f = f;
    unsigned int r = c.i + 0x7FFFu + ((c.i >> 16) & 1u);   // RNE
    return (bf16_t)(r >> 16);
}

__device__ __forceinline__ void storeC(float* p, float v)  { *p = v; }
__device__ __forceinline__ void storeC(bf16_t* p, float v) { *p = f2b(v); }

using bf16x8 = __attribute__((ext_vector_type(8))) short;
using f32x4  = __attribute__((ext_vector_type(4))) float;

// ---------------------------------------------------------------------------
// fp32 -> bf16 elementwise (4 elems/thread)
// ---------------------------------------------------------------------------
__global__ __launch_bounds__(256) void f32_to_bf16_kernel(
    const float* __restrict__ src, bf16_t* __restrict__ dst, int n4)
{
    const int i = blockIdx.x * 256 + threadIdx.x;
    if (i < n4) {
        float4 v = *(const float4*)(src + (size_t)i * 4);
        ushort4 o = {f2b(v.x), f2b(v.y), f2b(v.z), f2b(v.w)};
        *(ushort4*)(dst + (size_t)i * 4) = o;
    }
}

// ---------------------------------------------------------------------------
// fp32 [R][C] -> bf16 [C][R] transpose (32x32 LDS tile, block 32x8)
// ---------------------------------------------------------------------------
__global__ __launch_bounds__(256) void transpose_f32_bf16_kernel(
    const float* __restrict__ src, bf16_t* __restrict__ dst, int R, int C)
{
    __shared__ float t[32][33];
    const int c0 = blockIdx.x * 32, r0 = blockIdx.y * 32;
    for (int i = threadIdx.y; i < 32; i += 8)
        t[i][threadIdx.x] = src[(size_t)(r0 + i) * C + c0 + threadIdx.x];
    __syncthreads();
    for (int i = threadIdx.y; i < 32; i += 8)
        dst[(size_t)(c0 + i) * R + r0 + threadIdx.x] = f2b(t[threadIdx.x][i]);
}

// ---------------------------------------------------------------------------
// 256x256 8-phase MFMA bf16 GEMM (T1+T2+T3+T4+T5): C = A @ Bt^T + bias.
// 8 waves (2M x 4N), BK=64, double-buffered 128 KiB LDS, XOR-swizzled LDS,
// counted vmcnt(4) once per K-tile, XCD-aware blockIdx swizzle.
// ---------------------------------------------------------------------------
#if HAS_GLD
#define SGA(tt, hb, dst)                                                       \
    GLD16(gAb + (size_t)((hb) * 128) * K + (size_t)(tt) * 64,                  \
          (dst) + (((hb) * 128 + w * 16) * 64));                               \
    GLD16(gAb + (size_t)((hb) * 128 + 8) * K + (size_t)(tt) * 64,              \
          (dst) + (((hb) * 128 + w * 16 + 8) * 64))
#define SGB(tt, hb, dst)                                                       \
    GLD16(gBb + (size_t)((hb) * 128) * K + (size_t)(tt) * 64,                  \
          (dst) + (((hb) * 128 + w * 16) * 64));                               \
    GLD16(gBb + (size_t)((hb) * 128 + 8) * K + (size_t)(tt) * 64,              \
          (dst) + (((hb) * 128 + w * 16 + 8) * 64))
#else
#define SGA(tt, hb, dst)                                                       \
    *(bf16x8*)((dst) + (((hb) * 128 + w * 16) * 64) + lane * 8) =              \
        *(const bf16x8*)(gAb + (size_t)((hb) * 128) * K + (size_t)(tt) * 64);  \
    *(bf16x8*)((dst) + (((hb) * 128 + w * 16 + 8) * 64) + lane * 8) =          \
        *(const bf16x8*)(gAb + (size_t)((hb) * 128 + 8) * K + (size_t)(tt) * 64)
#define SGB(tt, hb, dst)                                                       \
    *(bf16x8*)((dst) + (((hb) * 128 + w * 16) * 64) + lane * 8) =              \
        *(const bf16x8*)(gBb + (size_t)((hb) * 128) * K + (size_t)(tt) * 64);  \
    *(bf16x8*)((dst) + (((hb) * 128 + w * 16 + 8) * 64) + lane * 8) =          \
        *(const bf16x8*)(gBb + (size_t)((hb) * 128 + 8) * K + (size_t)(tt) * 64)
#endif

#define PHASE(ABUF, p, STAGE, ENDWAIT)                                         \
  {                                                                            \
    bf16x8 a0k0 = *(const bf16x8*)&(ABUF)[aRow0 + (2*(p))   * 1024 + csw[0]];  \
    bf16x8 a0k1 = *(const bf16x8*)&(ABUF)[aRow0 + (2*(p))   * 1024 + csw[1]];  \
    bf16x8 a1k0 = *(const bf16x8*)&(ABUF)[aRow0 + (2*(p)+1) * 1024 + csw[0]];  \
    bf16x8 a1k1 = *(const bf16x8*)&(ABUF)[aRow0 + (2*(p)+1) * 1024 + csw[1]];  \
    STAGE;                                                                     \
    __builtin_amdgcn_s_barrier();                                              \
    asm volatile("s_waitcnt lgkmcnt(0)" ::: "memory");                         \
    __builtin_amdgcn_s_setprio(1);                                             \
    _Pragma("unroll")                                                          \
    for (int fn = 0; fn < 4; ++fn) {                                           \
      acc[2*(p)][fn]   = __builtin_amdgcn_mfma_f32_16x16x32_bf16(              \
          a0k0, bq[fn][0], acc[2*(p)][fn], 0, 0, 0);                           \
      acc[2*(p)][fn]   = __builtin_amdgcn_mfma_f32_16x16x32_bf16(              \
          a0k1, bq[fn][1], acc[2*(p)][fn], 0, 0, 0);                           \
      acc[2*(p)+1][fn] = __builtin_amdgcn_mfma_f32_16x16x32_bf16(              \
          a1k0, bq[fn][0], acc[2*(p)+1][fn], 0, 0, 0);                         \
      acc[2*(p)+1][fn] = __builtin_amdgcn_mfma_f32_16x16x32_bf16(              \
          a1k1, bq[fn][1], acc[2*(p)+1][fn], 0, 0, 0);                         \
    }                                                                          \
    __builtin_amdgcn_s_setprio(0);                                             \
    ENDWAIT;                                                                   \
    __builtin_amdgcn_s_barrier();                                              \
    asm volatile("" ::: "memory");                                             \
  }

#define KTILE(ABUF, BBUF, NABUF, t)                                            \
  {                                                                            \
    bf16x8 bq[4][2];                                                           \
    _Pragma("unroll")                                                          \
    for (int fn = 0; fn < 4; ++fn) {                                           \
      bq[fn][0] = *(const bf16x8*)&(BBUF)[bRow0 + fn * 1024 + csw[0]];         \
      bq[fn][1] = *(const bf16x8*)&(BBUF)[bRow0 + fn * 1024 + csw[1]];         \
    }                                                                          \
    const bool stA = ((t) + 1 < KT), stB = ((t) + 2 < KT);                     \
    PHASE(ABUF, 0, if (stA) { SGA((t) + 1, 0, NABUF); }, )                     \
    PHASE(ABUF, 1, if (stA) { SGA((t) + 1, 1, NABUF); }, )                     \
    PHASE(ABUF, 2, if (stB) { SGB((t) + 2, 0, BBUF); }, )                      \
    PHASE(ABUF, 3, if (stB) { SGB((t) + 2, 1, BBUF); },                        \
          if ((t) + 1 < KT) {                                                  \
            if (stB) { asm volatile("s_waitcnt vmcnt(4)" ::: "memory"); }      \
            else     { asm volatile("s_waitcnt vmcnt(0)" ::: "memory"); }      \
          })                                                                   \
  }

template<typename TC>
__global__ __launch_bounds__(512, 2) void gemm256_8phase_kernel(
    const bf16_t* __restrict__ A, const bf16_t* __restrict__ Bt,
    const float* __restrict__ bias, TC* __restrict__ C,
    int M, int N, int K)
{
    // [buf][A|B][256 rows][64 cols] bf16 = 128 KiB
    __shared__ __align__(16) short sm[65536];
    short* const smA0 = sm;
    short* const smB0 = sm + 16384;
    short* const smA1 = sm + 32768;
    short* const smB1 = sm + 49152;

    const int tid  = threadIdx.x;
    const int lane = tid & 63;
    const int w    = tid >> 6;            // 8 waves: 2 (M) x 4 (N)
    const int wr   = w >> 2, wc = w & 3;
    const int ml   = lane & 15, q2 = lane >> 4;

    // T1: XCD-aware blockIdx swizzle (bijective when nwg % 8 == 0)
    const int gx  = gridDim.x;
    const int nwg = gx * gridDim.y;
    const int bid = blockIdx.y * gx + blockIdx.x;
    int swz = bid;
    if ((nwg & 7) == 0) swz = (bid & 7) * (nwg >> 3) + (bid >> 3);
    const int m0 = (swz / gx) * 256, n0 = (swz % gx) * 256;

    const int KT   = K >> 6;              // K-tiles of 64 (even; K=1024 -> 16)

    // ds_read addressing (swizzled: 16B-chunk ^= row&7; row&7 == ml&7)
    int csw[2];
    csw[0] = ((q2)     ^ (ml & 7)) * 8;
    csw[1] = ((4 + q2) ^ (ml & 7)) * 8;
    const int aRow0 = (wr * 128 + ml) * 64;
    const int bRow0 = (wc * 64  + ml) * 64;

    // staging source (pre-swizzled global address; gload_lds dest is linear)
    const int rl   = lane >> 3;                       // row-in-8
    const int scol = ((lane & 7) ^ rl) * 8;           // swizzled k-chunk
    const bf16_t* gAb = A  + (size_t)(m0 + w * 16 + rl) * K + scol;
    const bf16_t* gBb = Bt + (size_t)(n0 + w * 16 + rl) * K + scol;

    f32x4 acc[8][4];
    #pragma unroll
    for (int i = 0; i < 8; ++i)
        #pragma unroll
        for (int j = 0; j < 4; ++j)
            acc[i][j] = {0.f, 0.f, 0.f, 0.f};

    // prologue: A(0), B(0) -> buf0; B(1) -> buf1; wait all but B(1)'s 4 loads
    SGA(0, 0, smA0); SGA(0, 1, smA0);
    SGB(0, 0, smB0); SGB(0, 1, smB0);
    SGB(1, 0, smB1); SGB(1, 1, smB1);
    asm volatile("s_waitcnt vmcnt(4)" ::: "memory");
    __builtin_amdgcn_s_barrier();
    asm volatile("" ::: "memory");

    for (int t = 0; t < KT; t += 2) {
        KTILE(smA0, smB0, smA1, t);
        KTILE(smA1, smB1, smA0, t + 1);
    }

    // epilogue
    float bv[4];
    #pragma unroll
    for (int fn = 0; fn < 4; ++fn)
        bv[fn] = bias[n0 + wc * 64 + fn * 16 + ml];
    #pragma unroll
    for (int fm = 0; fm < 8; ++fm)
        #pragma unroll
        for (int fn = 0; fn < 4; ++fn)
            #pragma unroll
            for (int r = 0; r < 4; ++r) {
                const int row = m0 + wr * 128 + fm * 16 + q2 * 4 + r;
                const int col = n0 + wc * 64  + fn * 16 + ml;
                storeC(&C[(size_t)row * N + col], acc[fm][fn][r] + bv[fn]);
            }
}

#undef KTILE
#undef PHASE
#undef SGA
#undef SGB

// ---------------------------------------------------------------------------
// Block means: 4 waves/block, stride-4 token partition + LDS reduce.
// ---------------------------------------------------------------------------
__global__ __launch_bounds__(256) void block_repr_kernel(
    const bf16_t* __restrict__ qkv,
    float* __restrict__ q_repr, float* __restrict__ k_repr)
{
    __shared__ float red[2][4][64];
    const int blk = blockIdx.x;
    const int n  = blk & 63;
    const int bh = blk >> 6;
    const int h  = bh & 15, b = bh >> 4;
    const int d  = threadIdx.x & 63;
    const int ss = threadIdx.x >> 6;     // wave id 0..3
    const bf16_t* base = qkv + (size_t)(b * L_ + n * BS_) * (3 * D_) + h * HD_ + d;
    float sq = 0.f, sk = 0.f;
    for (int s = ss; s < BS_; s += 4) {
        sq += b2f(base[(size_t)s * (3 * D_)]);
        sk += b2f(base[(size_t)s * (3 * D_) + D_]);
    }
    red[0][ss][d] = sq;
    red[1][ss][d] = sk;
    __syncthreads();
    if (threadIdx.x < 64) {
        const int dd = threadIdx.x;
        q_repr[(size_t)blk * HD_ + dd] =
            (red[0][0][dd] + red[0][1][dd] + red[0][2][dd] + red[0][3][dd])
            * (1.0f / BS_);
    } else if (threadIdx.x < 128) {
        const int dd = threadIdx.x - 64;
        k_repr[(size_t)blk * HD_ + dd] =
            (red[1][0][dd] + red[1][1][dd] + red[1][2][dd] + red[1][3][dd])
            * (1.0f / BS_);
    }
}

// ---------------------------------------------------------------------------
// Gumbel-Sinkhorn: one block of 256 threads per (b,h). Thread (r, sub=tid&3)
// owns 16 elements (m = 4*mi+sub) of row r (row pass / sim) or col r (col
// pass). 4-lane __shfl_xor completes the 64-wide logsumexp.
// ---------------------------------------------------------------------------
__global__ __launch_bounds__(256) void sinkhorn_kernel(
    const float* __restrict__ q_repr, const float* __restrict__ k_repr,
    const float* __restrict__ gumbel, bf16_t* __restrict__ P_bf)
{
    __shared__ __align__(16) float qr[64 * 68];
    __shared__ __align__(16) float kr[64 * 68];
    __shared__ float la[64 * 65];
    const int bh  = blockIdx.x;
    const int tid = threadIdx.x;
    const int r   = tid >> 2;            // 0..63
    const int sub = tid & 3;

    for (int idx = tid; idx < 4096; idx += 256) {
        const int rr = idx >> 6, cc = idx & 63;
        qr[rr * 68 + cc] = q_repr[(size_t)bh * 4096 + idx];
        kr[rr * 68 + cc] = k_repr[(size_t)bh * 4096 + idx];
    }
    __syncthreads();

    // sim init: thread computes cols m = 4*mi+sub of row r
    {
        float acc[16];
        #pragma unroll
        for (int mi = 0; mi < 16; ++mi) acc[mi] = 0.f;
        for (int d4 = 0; d4 < 16; ++d4) {
            const float4 q = *(const float4*)&qr[r * 68 + d4 * 4];
            #pragma unroll
            for (int mi = 0; mi < 16; ++mi) {
                const float4 kv = *(const float4*)&kr[(4 * mi + sub) * 68 + d4 * 4];
                acc[mi] += q.x * kv.x + q.y * kv.y + q.z * kv.z + q.w * kv.w;
            }
        }
        #pragma unroll
        for (int mi = 0; mi < 16; ++mi) {
            const int m = 4 * mi + sub;
            la[r * 65 + m] = (acc[mi] * SCALE_
                + gumbel[(size_t)bh * 4096 + r * 64 + m]) * INV_TEMP;
        }
    }
    __syncthreads();

    for (int it = 0; it < 7; ++it) {
        {   // row pass: normalize row r over m
            float v[16];
            #pragma unroll
            for (int mi = 0; mi < 16; ++mi) v[mi] = la[r * 65 + 4 * mi + sub];
            float mx = v[0];
            #pragma unroll
            for (int mi = 1; mi < 16; ++mi) mx = fmaxf(mx, v[mi]);
            mx = fmaxf(mx, __shfl_xor(mx, 1, 64));
            mx = fmaxf(mx, __shfl_xor(mx, 2, 64));
            float sum = 0.f;
            #pragma unroll
            for (int mi = 0; mi < 16; ++mi) sum += expf(v[mi] - mx);
            sum += __shfl_xor(sum, 1, 64);
            sum += __shfl_xor(sum, 2, 64);
            const float lse = mx + logf(sum);
            #pragma unroll
            for (int mi = 0; mi < 16; ++mi) la[r * 65 + 4 * mi + sub] = v[mi] - lse;
        }
        __syncthreads();
        {   // col pass: normalize col r over rows
            float v[16];
            #pragma unroll
            for (int mi = 0; mi < 16; ++mi) v[mi] = la[(4 * mi + sub) * 65 + r];
            float mx = v[0];
            #pragma unroll
            for (int mi = 1; mi < 16; ++mi) mx = fmaxf(mx, v[mi]);
            mx = fmaxf(mx, __shfl_xor(mx, 1, 64));
            mx = fmaxf(mx, __shfl_xor(mx, 2, 64));
            float sum = 0.f;
            #pragma unroll
            for (int mi = 0; mi < 16; ++mi) sum += expf(v[mi] - mx);
            sum += __shfl_xor(sum, 1, 64);
            sum += __shfl_xor(sum, 2, 64);
            const float lse = mx + logf(sum);
            #pragma unroll
            for (int mi = 0; mi < 16; ++mi)
                la[(4 * mi + sub) * 65 + r] = v[mi] - lse;
        }
        __syncthreads();
    }

    #pragma unroll
    for (int mi = 0; mi < 16; ++mi) {
        const int m = 4 * mi + sub;
        P_bf[(size_t)bh * 4096 + r * 64 + m] = f2b(expf(la[r * 65 + m]));
    }
}

// ---------------------------------------------------------------------------
// MFMA soft-sort: per (b,h): out[n,f] = sum_m P[n,m] * src[m,f], f = s*64+d.
// Barrier-free: P A-frags read directly from global (8 KB/bh, L2-hot,
// reused by 16 c-blocks); K/V rows staged into a wave-PRIVATE LDS slice
// [64][66] (stride 66 shorts -> the hot 128 scalar gather reads/thread are
// bank-conflict-free: quad offsets {0,8,16,24} + (ml>>1) span all 32 banks).
// LDS 33 KB -> 4 blocks/CU.
// ---------------------------------------------------------------------------
__global__ __launch_bounds__(256) void sort_kv_mfma_kernel(
    const bf16_t* __restrict__ P_bf, const bf16_t* __restrict__ qkv,
    bf16_t* __restrict__ k_sorted, bf16_t* __restrict__ v_sorted)
{
    constexpr int RS = 66;               // K/V row stride (shorts)
    __shared__ __align__(16) short Kst[4 * 64 * RS];
    const int tid = threadIdx.x, lane = tid & 63, w = tid >> 6;
    const int bh = blockIdx.y;
    const int h = bh & 15, b = bh >> 4;
    const int c = blockIdx.x;
    const int ml = lane & 15, q8 = (lane >> 4) * 8;

    const bf16_t* ps = P_bf + (size_t)bh * (NB_ * NB_);

    const int s = c * 4 + w;                       // token index within block
    const int fbase = c * 256 + w * 64;
    short* Kw = &Kst[w * 64 * RS];                 // wave-private slice
    const int srow = lane >> 3;                    // row-in-8 for staging
    const int sc8  = (lane & 7) * 8;               // 16 B segment

    for (int kv = 0; kv < 2; ++kv) {
        const bf16_t* src = qkv + ((size_t)(b * L_ + s)) * (3 * D_)
                          + (kv ? 2 * D_ : 1 * D_) + h * HD_;

        // stage 64 rows x 128 B into LDS (8 rows per wave-load)
        #pragma unroll
        for (int g = 0; g < 8; ++g) {
            const int m = g * 8 + srow;
            *(bf16x8*)&Kw[m * RS + sc8] =
                *(const bf16x8*)(src + (size_t)m * (BS_ * 3 * D_) + sc8);
        }

        // B-frags from LDS: bt[t][kt][j] = row(kt*32+q8+j), d = t*16+ml
        bf16x8 bt[4][2];
        #pragma unroll
        for (int kt = 0; kt < 2; ++kt)
            #pragma unroll
            for (int j = 0; j < 8; ++j) {
                const short* rp = &Kw[(kt * 32 + q8 + j) * RS + ml];
                #pragma unroll
                for (int t = 0; t < 4; ++t)
                    bt[t][kt][j] = rp[t * 16];
            }

        f32x4 acc[4][4];
        #pragma unroll
        for (int nt = 0; nt < 4; ++nt)
            #pragma unroll
            for (int t = 0; t < 4; ++t)
                acc[nt][t] = {0.f, 0.f, 0.f, 0.f};

        #pragma unroll
        for (int nt = 0; nt < 4; ++nt) {
            bf16x8 a0 = *(const bf16x8*)&ps[(size_t)(nt * 16 + ml) * 64 + q8];
            bf16x8 a1 = *(const bf16x8*)&ps[(size_t)(nt * 16 + ml) * 64 + 32 + q8];
            #pragma unroll
            for (int t = 0; t < 4; ++t) {
                acc[nt][t] = __builtin_amdgcn_mfma_f32_16x16x32_bf16(
                    a0, bt[t][0], acc[nt][t], 0, 0, 0);
                acc[nt][t] = __builtin_amdgcn_mfma_f32_16x16x32_bf16(
                    a1, bt[t][1], acc[nt][t], 0, 0, 0);
            }
        }

        // store: n = nt*16 + quad*4 + reg, f = fbase + t*16 + ml
        bf16_t* dst = (kv ? v_sorted : k_sorted) + (size_t)bh * (NB_ * BS_ * HD_);
        const int quad4 = (lane >> 4) * 4;
        #pragma unroll
        for (int nt = 0; nt < 4; ++nt)
            #pragma unroll
            for (int t = 0; t < 4; ++t)
                #pragma unroll
                for (int r = 0; r < 4; ++r)
                    dst[(size_t)(nt * 16 + quad4 + r) * (BS_ * HD_)
                        + fbase + t * 16 + ml] = f2b(acc[nt][t][r]);
    }
}

// ---------------------------------------------------------------------------
// MFMA block attention. Psh ALIASES Ks (P is written only after QK^T is done
// reading Ks; enforced by an extra __syncthreads). LDS 35 KB -> 4 blocks/CU.
// ---------------------------------------------------------------------------
__global__ __launch_bounds__(256) void attn_mfma_kernel(
    const bf16_t* __restrict__ qkv, const bf16_t* __restrict__ k_sorted,
    const bf16_t* __restrict__ v_sorted, bf16_t* __restrict__ attn_out)
{
    constexpr int KS = 72, VS = 136, PS = 136;
    __shared__ short Ks[128 * KS];       // also Psh (64*PS = 8704 <= 9216)
    __shared__ short Vt[64 * VS];
    short* const Psh = Ks;
    const int tid = threadIdx.x, lane = tid & 63, w = tid >> 6;
    const int n  = blockIdx.x & 63;
    const int bh = blockIdx.x >> 6;
    const int h = bh & 15, b = bh >> 4;
    const bool last = (n == NB_ - 1);

    const bf16_t* qb = qkv + (size_t)(b * L_ + n * BS_) * (3 * D_) + h * HD_;
    const bf16_t* kb = qb + D_;
    const bf16_t* vb = qb + 2 * D_;
    const size_t nextoff = ((size_t)bh * NB_ + (n + 1)) * (size_t)(BS_ * HD_);
    const bf16_t* kn = k_sorted + nextoff;
    const bf16_t* vn = v_sorted + nextoff;

    {
        const int col8 = (tid & 7) * 8, r0 = tid >> 3;
        const int jjmax = last ? 2 : 4;
        for (int jj = 0; jj < jjmax; ++jj) {
            const int row = jj * 32 + r0;
            const bf16_t* src = (row < 64)
                ? kb + (size_t)row * (3 * D_) + col8
                : kn + (size_t)(row - 64) * HD_ + col8;
            *(bf16x8*)&Ks[row * KS + col8] = *(const bf16x8*)src;
        }
    }
    {
        const int halves = last ? 1 : 2;
        for (int half = 0; half < halves; ++half) {
            for (int jj = 0; jj < 4; ++jj) {
                const int d0 = jj * 16 + w * 4;
                const bf16_t* src = (half == 0)
                    ? vb + (size_t)lane * (3 * D_) + d0
                    : vn + (size_t)lane * HD_ + d0;
                ushort4 u = *(const ushort4*)src;
                const int kcol = half * 64 + lane;
                Vt[(d0 + 0) * VS + kcol] = u.x;
                Vt[(d0 + 1) * VS + kcol] = u.y;
                Vt[(d0 + 2) * VS + kcol] = u.z;
                Vt[(d0 + 3) * VS + kcol] = u.w;
            }
        }
    }

    const int ml = lane & 15, quad = lane >> 4, q8 = quad * 8;
    const int m0 = w * 16;

    bf16x8 af0 = *(const bf16x8*)(qb + (size_t)(m0 + ml) * (3 * D_) + q8);
    bf16x8 af1 = *(const bf16x8*)(qb + (size_t)(m0 + ml) * (3 * D_) + 32 + q8);

    __syncthreads();

    const int ntile = last ? 4 : 8;
    f32x4 st[8];
    #pragma unroll
    for (int t = 0; t < 8; ++t) st[t] = {0.f, 0.f, 0.f, 0.f};
    for (int t = 0; t < ntile; ++t) {
        bf16x8 b0 = *(const bf16x8*)&Ks[(t * 16 + ml) * KS + q8];
        bf16x8 b1 = *(const bf16x8*)&Ks[(t * 16 + ml) * KS + 32 + q8];
        st[t] = __builtin_amdgcn_mfma_f32_16x16x32_bf16(af0, b0, st[t], 0, 0, 0);
        st[t] = __builtin_amdgcn_mfma_f32_16x16x32_bf16(af1, b1, st[t], 0, 0, 0);
    }

    __syncthreads();   // all waves done reading Ks -> safe to write Psh(=Ks)

    #pragma unroll
    for (int reg = 0; reg < 4; ++reg) {
        float mx = -1e30f;
        for (int t = 0; t < ntile; ++t) mx = fmaxf(mx, st[t][reg] * SCALE_);
        #pragma unroll
        for (int xm = 1; xm <= 8; xm <<= 1)
            mx = fmaxf(mx, __shfl_xor(mx, xm, 64));
        float e[8];
        float sum = 0.f;
        for (int t = 0; t < ntile; ++t) {
            e[t] = __expf(st[t][reg] * SCALE_ - mx);
            sum += e[t];
        }
        #pragma unroll
        for (int xm = 1; xm <= 8; xm <<= 1)
            sum += __shfl_xor(sum, xm, 64);
        const float inv = 1.0f / sum;
        const int qrow = m0 + quad * 4 + reg;
        for (int t = 0; t < ntile; ++t)
            Psh[qrow * PS + t * 16 + ml] = f2b(e[t] * inv);
    }

    __syncthreads();

    const int ktv = last ? 2 : 4;
    f32x4 oacc[4];
    #pragma unroll
    for (int t = 0; t < 4; ++t) oacc[t] = {0.f, 0.f, 0.f, 0.f};
    for (int kt = 0; kt < ktv; ++kt) {
        bf16x8 pa = *(const bf16x8*)&Psh[(m0 + ml) * PS + kt * 32 + q8];
        #pragma unroll
        for (int t = 0; t < 4; ++t) {
            bf16x8 vf = *(const bf16x8*)&Vt[(t * 16 + ml) * VS + kt * 32 + q8];
            oacc[t] = __builtin_amdgcn_mfma_f32_16x16x32_bf16(pa, vf, oacc[t], 0, 0, 0);
        }
    }

    bf16_t* ob = attn_out + (size_t)(b * L_ + n * BS_) * D_ + h * HD_;
    #pragma unroll
    for (int t = 0; t < 4; ++t)
        #pragma unroll
        for (int reg = 0; reg < 4; ++reg) {
            const int qrow = m0 + quad * 4 + reg;
            ob[(size_t)qrow * D_ + t * 16 + ml] = f2b(oacc[t][reg]);
        }
}

// ---------------------------------------------------------------------------
extern "C" void kernel_launch(void* const* d_in, const int* in_sizes, int n_in,
                              void* d_out, int out_size, void* d_ws, size_t ws_size,
                              hipStream_t stream)
{
    const float* x      = (const float*)d_in[0];
    const float* gumbel = (const float*)d_in[1];
    const float* W_qkv  = (const float*)d_in[2];
    const float* b_qkv  = (const float*)d_in[3];
    const float* W_out  = (const float*)d_in[4];
    const float* b_out  = (const float*)d_in[5];
    float* out = (float*)d_out;

    const size_t need = 204472320ull;
    if (ws_size < need) {
        fprintf(stderr, "[kernel_launch] ws_size=%zu < need=%zu — aborting launch\n",
                ws_size, need);
        return;
    }

    bf16_t* qkv      = (bf16_t*)d_ws;
    bf16_t* attn_o   = qkv    + (size_t)B_ * L_ * 3 * D_;
    bf16_t* k_sorted = attn_o + (size_t)B_ * L_ * D_;
    bf16_t* v_sorted = k_sorted + (size_t)B_ * L_ * D_;
    float* q_repr    = (float*)(v_sorted + (size_t)B_ * L_ * D_);
    float* k_repr    = q_repr + (size_t)B_ * H_ * NB_ * HD_;
    bf16_t* P_bf     = (bf16_t*)(k_repr + (size_t)B_ * H_ * NB_ * HD_);

    bf16_t* x_bf   = (bf16_t*)d_out;               // d_out scratch until GEMM2
    bf16_t* Wqkv_t = x_bf + (size_t)B_ * L_ * D_;
    bf16_t* Wout_t = (bf16_t*)q_repr;              // dead after sinkhorn

    // 0a. x -> bf16
    f32_to_bf16_kernel<<<(B_ * L_ * D_ / 4 + 255) / 256, 256, 0, stream>>>(
        x, x_bf, B_ * L_ * D_ / 4);
    // 0b. W_qkv [1024,3072] -> Wqkv_t bf16 [3072,1024]
    transpose_f32_bf16_kernel<<<dim3(3 * D_ / 32, D_ / 32), dim3(32, 8), 0, stream>>>(
        W_qkv, Wqkv_t, D_, 3 * D_);

    // 1. QKV projection (256x256 8-phase MFMA bf16)
    gemm256_8phase_kernel<bf16_t>
        <<<dim3(3 * D_ / 256, B_ * L_ / 256), 512, 0, stream>>>(
        x_bf, Wqkv_t, b_qkv, qkv, B_ * L_, 3 * D_, D_);

    // 2. block means (4 waves/block)
    block_repr_kernel<<<B_ * H_ * NB_, 256, 0, stream>>>(qkv, q_repr, k_repr);

    // 3. Gumbel-Sinkhorn -> P (bf16), 256 threads/block
    sinkhorn_kernel<<<B_ * H_, 256, 0, stream>>>(q_repr, k_repr, gumbel, P_bf);

    // 4. soft-sort K/V blocks (MFMA, barrier-free, 4 blk/CU)
    sort_kv_mfma_kernel<<<dim3(16, B_ * H_), 256, 0, stream>>>(
        P_bf, qkv, k_sorted, v_sorted);

    // 5. block-local attention (MFMA, Psh-aliased, 4 blk/CU)
    attn_mfma_kernel<<<B_ * H_ * NB_, 256, 0, stream>>>(
        qkv, k_sorted, v_sorted, attn_o);

    // 5b. W_out -> Wout_t bf16 [1024,1024]
    transpose_f32_bf16_kernel<<<dim3(D_ / 32, D_ / 32), dim3(32, 8), 0, stream>>>(
        W_out, Wout_t, D_, D_);

    // 6. output projection (256x256 8-phase MFMA bf16) -> fp32
    gemm256_8phase_kernel<float>
        <<<dim3(D_ / 256, B_ * L_ / 256), 512, 0, stream>>>(
        attn_o, Wout_t, b_out, out, B_ * L_, D_, D_);
}